// Round 11
// baseline (321.737 us; speedup 1.0000x reference)
//
#include <hip/hip_runtime.h>
#include <stdint.h>

#define NL  16
#define NE  16384               // entries per level (power of two)
#define NB  64                  // chunks per level in pass 1 (load-balance elasticity)
#define BLK1 512                // pass-1 threads per block
#define PPB  ((1 << 21) / NB)   // 32768 points per pass-1 block
#define ITER (PPB / BLK1)       // 64 points per thread
#define BLK2 256                // pass-2 threads per block (2 points per thread)
#define BLKF 1024               // fallback threads per block

constexpr int kRes[NL] = {16,20,25,32,40,50,64,80,101,128,161,203,256,322,406,512};
__device__ const int dRes[NL] = {16,20,25,32,40,50,64,80,101,128,161,203,256,322,406,512};

// ---------------- pre-pass: pack emb (L,2,NE) fp32 -> (L,NE) u32 of 2x bf16 ----------------
__global__ void pack_kernel(const float* __restrict__ emb, uint32_t* __restrict__ tbl) {
    int i = blockIdx.x * blockDim.x + threadIdx.x;     // 0 .. NL*NE-1
    if (i >= NL * NE) return;
    int l = i >> 14;
    int j = i & (NE - 1);
    float e0 = emb[(size_t)l * 2 * NE + j];
    float e1 = emb[(size_t)l * 2 * NE + NE + j];
    uint32_t u0 = __float_as_uint(e0); u0 = (u0 + 0x7fffu + ((u0 >> 16) & 1u)) >> 16;  // RTNE bf16
    uint32_t u1 = __float_as_uint(e1); u1 = (u1 + 0x7fffu + ((u1 >> 16) & 1u)) >> 16;
    tbl[i] = u0 | (u1 << 16);
}

// ---------------- pass 1: LEVEL-MAJOR, table staged once, barrier-free gather loop ----------------
// level = bid & 15 (interleaved for CU/XCD balance), chunk = bid >> 4. 1024 blocks, 2/CU resident.
// Hashed levels skip coordinate clamping: invalid corners carry w=0, and the masked hash of the
// raw coord stays in [0,NE) -> gathered garbage * 0 = 0 (table values finite, no NaN).
__global__ __launch_bounds__(BLK1, 4)   // 64-VGPR budget
void level_kernel(const float* __restrict__ x, const uint32_t* __restrict__ tbl,
                  uint32_t* __restrict__ mid) {
    __shared__ __align__(16) uint32_t lds[NE];         // 64 KB: this level's full table

    const int tid   = threadIdx.x;
    const int level = blockIdx.x & (NL - 1);
    const int chunk = blockIdx.x >> 4;

    // stage this level's table once (512 thr x 8 x 16 B = 64 KB)
    {
        const uint4* g = (const uint4*)(tbl + ((size_t)level << 14));
        uint4* dst = (uint4*)lds;
        #pragma unroll
        for (int p = 0; p < 8; ++p) dst[p * BLK1 + tid] = g[p * BLK1 + tid];
    }
    __syncthreads();                                   // only barrier in the kernel

    const int   res  = dRes[level];
    const float hres = 0.5f * (float)res;              // unnorm: ix = p*hres + (hres-0.5)
    const float cadd = hres - 0.5f;
    const bool hashed = (res * res * res > NE);

    uint32_t* dst = mid + ((size_t)level << 21);
    const float3* xs = (const float3*)x;
    const size_t pbase = (size_t)chunk * PPB + tid;

    if (hashed) {
        float3 nxt = xs[pbase];
        for (int i = 0; i < ITER; ++i) {
            const float3 cur = nxt;
            if (i + 1 < ITER) nxt = xs[pbase + (size_t)(i + 1) * BLK1];  // preload: latency
            const float pc[3] = {cur.x, cur.y, cur.z};                   // hides under gathers

            float    w[3][2];
            uint32_t a[3][2];
            #pragma unroll
            for (int d = 0; d < 3; ++d) {
                constexpr uint32_t P[3] = {1u, 2654435761u, 805459861u};
                float ix = fmaf(pc[d], hres, cadd);
                float fl = floorf(ix);
                const float fr = ix - fl;
                const int lo = (int)fl;                 // in [-1, res-1], NO clamp
                w[d][0] = (lo >= 0)       ? (1.0f - fr) : 0.0f;   // zero-padding
                w[d][1] = (lo + 1 <= res - 1) ? fr      : 0.0f;
                a[d][0] = (uint32_t)lo * P[d];
                a[d][1] = a[d][0] + P[d];
            }

            float    wxy[4];
            uint32_t axy[4];
            #pragma unroll
            for (int c = 0; c < 4; ++c) {
                wxy[c] = w[0][c & 1] * w[1][(c >> 1) & 1];
                axy[c] = a[0][c & 1] ^ a[1][(c >> 1) & 1];
            }

            float f0 = 0.0f, f1 = 0.0f;
            #pragma unroll
            for (int c = 0; c < 8; ++c) {
                const int cxy = c & 3, bz = (c >> 2) & 1;
                const uint32_t idx = (axy[cxy] ^ a[2][bz]) & (uint32_t)(NE - 1);
                const float wt = wxy[cxy] * w[2][bz];
                const uint32_t v = lds[idx];
                f0 = fmaf(wt, __uint_as_float(v << 16),          f0);
                f1 = fmaf(wt, __uint_as_float(v & 0xffff0000u),  f1);
            }

            const uint32_t u0 = (__float_as_uint(f0) + 0x8000u) >> 16;
            const uint32_t u1 = (__float_as_uint(f1) + 0x8000u) & 0xffff0000u;
            dst[pbase + (size_t)i * BLK1] = u0 | u1;
        }
    } else {                                            // direct levels (0..2): clamps needed
        const uint32_t sy = (uint32_t)res, sz = (uint32_t)(res * res);
        float3 nxt = xs[pbase];
        for (int i = 0; i < ITER; ++i) {
            const float3 cur = nxt;
            if (i + 1 < ITER) nxt = xs[pbase + (size_t)(i + 1) * BLK1];
            const float pc[3] = {cur.x, cur.y, cur.z};

            float    w[3][2];
            uint32_t a[3][2];
            #pragma unroll
            for (int d = 0; d < 3; ++d) {
                const uint32_t stride = (d == 0) ? 1u : ((d == 1) ? sy : sz);
                float ix = fmaf(pc[d], hres, cadd);
                float fl = floorf(ix);
                const float fr = ix - fl;
                const int lo = (int)fl, hi = lo + 1;
                w[d][0] = (lo >= 0)       ? (1.0f - fr) : 0.0f;
                w[d][1] = (hi <= res - 1) ? fr          : 0.0f;
                const int loc = lo < 0 ? 0 : lo;
                const int hic = hi > res - 1 ? res - 1 : hi;
                a[d][0] = (uint32_t)loc * stride;
                a[d][1] = (uint32_t)hic * stride;
            }

            float    wxy[4];
            uint32_t axy[4];
            #pragma unroll
            for (int c = 0; c < 4; ++c) {
                wxy[c] = w[0][c & 1] * w[1][(c >> 1) & 1];
                axy[c] = a[0][c & 1] + a[1][(c >> 1) & 1];
            }

            float f0 = 0.0f, f1 = 0.0f;
            #pragma unroll
            for (int c = 0; c < 8; ++c) {
                const int cxy = c & 3, bz = (c >> 2) & 1;
                const uint32_t idx = axy[cxy] + a[2][bz];
                const float wt = wxy[cxy] * w[2][bz];
                const uint32_t v = lds[idx];
                f0 = fmaf(wt, __uint_as_float(v << 16),          f0);
                f1 = fmaf(wt, __uint_as_float(v & 0xffff0000u),  f1);
            }

            const uint32_t u0 = (__float_as_uint(f0) + 0x8000u) >> 16;
            const uint32_t u1 = (__float_as_uint(f1) + 0x8000u) & 0xffff0000u;
            dst[pbase + (size_t)i * BLK1] = u0 | u1;
        }
    }
}

// ------------- pass 2: transpose (L,B) u32 -> (B,L,2) fp32; 2 points/thread -------------
__global__ __launch_bounds__(BLK2, 4)
void transpose_kernel(const uint32_t* __restrict__ mid, float* __restrict__ out) {
    const size_t t = (size_t)blockIdx.x * BLK2 + threadIdx.x;    // pair index: points 2t,2t+1
    uint2 v[NL];
    #pragma unroll
    for (int l = 0; l < NL; ++l)
        v[l] = ((const uint2*)(mid + ((size_t)l << 21)))[t];     // 16 streams, 8 B/thread each
    float4* o = (float4*)(out + t * 64);
    #pragma unroll
    for (int q = 0; q < 8; ++q) {                                // point 2t: one full 128-B line
        const uint32_t v0 = v[2 * q].x, v1 = v[2 * q + 1].x;
        o[q] = make_float4(__uint_as_float(v0 << 16), __uint_as_float(v0 & 0xffff0000u),
                           __uint_as_float(v1 << 16), __uint_as_float(v1 & 0xffff0000u));
    }
    #pragma unroll
    for (int q = 0; q < 8; ++q) {                                // point 2t+1: next line
        const uint32_t v0 = v[2 * q].y, v1 = v[2 * q + 1].y;
        o[8 + q] = make_float4(__uint_as_float(v0 << 16), __uint_as_float(v0 & 0xffff0000u),
                               __uint_as_float(v1 << 16), __uint_as_float(v1 & 0xffff0000u));
    }
}

// ---------------- fallback: R6 point-major kernel (proven ~230-260 us) if ws too small ----------------
__global__ __launch_bounds__(BLKF, 4)
void hashenc_kernel(const float* __restrict__ x, const uint32_t* __restrict__ tbl,
                    float* __restrict__ out) {
    __shared__ __align__(16) uint32_t lds[NE];

    const int tid  = threadIdx.x;
    const size_t b = (size_t)blockIdx.x * BLKF + tid;

    const float3 p3 = ((const float3*)x)[b];
    const float pc[3] = {p3.x, p3.y, p3.z};

    {
        const uint4* g = (const uint4*)tbl;
        uint4 r0 = g[0 * BLKF + tid], r1 = g[1 * BLKF + tid];
        uint4 r2 = g[2 * BLKF + tid], r3 = g[3 * BLKF + tid];
        uint4* dst = (uint4*)lds;
        dst[0 * BLKF + tid] = r0; dst[1 * BLKF + tid] = r1;
        dst[2 * BLKF + tid] = r2; dst[3 * BLKF + tid] = r3;
    }

    float acc[16];
    #pragma unroll
    for (int i = 0; i < 16; ++i) acc[i] = 0.0f;

    #pragma unroll
    for (int l = 0; l < NL; ++l) {
        __syncthreads();

        uint4 r0, r1, r2, r3;
        if (l + 1 < NL) {
            const uint4* g = (const uint4*)(tbl + ((size_t)(l + 1) << 14));
            r0 = g[0 * BLKF + tid]; r1 = g[1 * BLKF + tid];
            r2 = g[2 * BLKF + tid]; r3 = g[3 * BLKF + tid];
        }

        const int   res  = kRes[l];
        const float hres = 0.5f * (float)res;
        const float cadd = hres - 0.5f;
        const bool hashed = (res * res * res > NE);

        float fr[3]; int c0[3];
        #pragma unroll
        for (int d = 0; d < 3; ++d) {
            float ix = fmaf(pc[d], hres, cadd);
            float fl = floorf(ix);
            fr[d] = ix - fl;
            c0[d] = (int)fl;
        }

        float    w[3][2];
        uint32_t a[3][2];
        #pragma unroll
        for (int d = 0; d < 3; ++d) {
            const int lo = c0[d], hi = c0[d] + 1;
            w[d][0] = (lo >= 0)     ? (1.0f - fr[d]) : 0.0f;
            w[d][1] = (hi <= res-1) ? fr[d]          : 0.0f;
            const int loc = lo < 0 ? 0 : lo;
            const int hic = hi > res - 1 ? res - 1 : hi;
            if (hashed) {
                constexpr uint32_t P[3] = {1u, 2654435761u, 805459861u};
                a[d][0] = (uint32_t)loc * P[d];
                a[d][1] = (uint32_t)hic * P[d];
            } else {
                const uint32_t stride = (d == 0) ? 1u : ((d == 1) ? (uint32_t)res
                                                                  : (uint32_t)(res * res));
                a[d][0] = (uint32_t)loc * stride;
                a[d][1] = (uint32_t)hic * stride;
            }
        }

        float    wxy[4];
        uint32_t axy[4];
        #pragma unroll
        for (int c = 0; c < 4; ++c) {
            const int bx = c & 1, by = (c >> 1) & 1;
            wxy[c] = w[0][bx] * w[1][by];
            axy[c] = hashed ? (a[0][bx] ^ a[1][by]) : (a[0][bx] + a[1][by]);
        }

        float f0 = 0.0f, f1 = 0.0f;
        #pragma unroll
        for (int c = 0; c < 8; ++c) {
            const int cxy = c & 3, bz = (c >> 2) & 1;
            const uint32_t idx = hashed
                ? ((axy[cxy] ^ a[2][bz]) & (uint32_t)(NE - 1))
                : (axy[cxy] + a[2][bz]);
            const float wt = wxy[cxy] * w[2][bz];
            const uint32_t v = lds[idx];
            f0 = fmaf(wt, __uint_as_float(v << 16),          f0);
            f1 = fmaf(wt, __uint_as_float(v & 0xffff0000u),  f1);
        }
        acc[2 * (l & 7) + 0] = f0;
        acc[2 * (l & 7) + 1] = f1;

        if (l + 1 < NL) {
            __syncthreads();
            uint4* dst = (uint4*)lds;
            dst[0 * BLKF + tid] = r0; dst[1 * BLKF + tid] = r1;
            dst[2 * BLKF + tid] = r2; dst[3 * BLKF + tid] = r3;
        }

        if ((l & 7) == 7) {
            float4* o = (float4*)(out + b * 32 + (size_t)(l >> 3) * 16);
            o[0] = make_float4(acc[0],  acc[1],  acc[2],  acc[3]);
            o[1] = make_float4(acc[4],  acc[5],  acc[6],  acc[7]);
            o[2] = make_float4(acc[8],  acc[9],  acc[10], acc[11]);
            o[3] = make_float4(acc[12], acc[13], acc[14], acc[15]);
        }
    }
}

extern "C" void kernel_launch(void* const* d_in, const int* in_sizes, int n_in,
                              void* d_out, int out_size, void* d_ws, size_t ws_size,
                              hipStream_t stream) {
    const float* x   = (const float*)d_in[0];   // (B,3) fp32
    const float* emb = (const float*)d_in[1];   // (16,2,16384) fp32
    float* out = (float*)d_out;                 // (B,16,2) fp32

    uint32_t* tbl = (uint32_t*)d_ws;            // (16,16384) packed bf16x2 = 1 MB
    const size_t tbl_bytes = (size_t)NL * NE * 4;
    const size_t mid_bytes = (size_t)NL * (1 << 21) * 4;   // 128 MB intermediate

    const int npack = NL * NE;
    pack_kernel<<<dim3((npack + 255) / 256), dim3(256), 0, stream>>>(emb, tbl);

    if (ws_size >= tbl_bytes + mid_bytes) {
        uint32_t* mid = tbl + (size_t)NL * NE;
        level_kernel<<<dim3(NL * NB), dim3(BLK1), 0, stream>>>(x, tbl, mid);
        transpose_kernel<<<dim3((1 << 21) / (2 * BLK2)), dim3(BLK2), 0, stream>>>(mid, out);
    } else {
        hashenc_kernel<<<dim3((1 << 21) / BLKF), dim3(BLKF), 0, stream>>>(x, tbl, out);
    }
}

// Round 12
// 183.630 us; speedup vs baseline: 1.7521x; 1.7521x over previous
//
#include <hip/hip_runtime.h>
#include <stdint.h>

#define NL  16
#define NE  16384               // entries per level (power of two)
#define NB  64                  // chunks per level in pass 1
#define BLK1 512                // pass-1 threads per block
#define PPB  ((1 << 21) / NB)   // 32768 points per pass-1 block
#define ITER (PPB / BLK1)       // 64 points per thread
#define BLK2 256                // pass-2 threads per block
#define TP   512                // pass-2 points per block (LDS tile)
#define BLKF 1024               // fallback threads per block

constexpr int kRes[NL] = {16,20,25,32,40,50,64,80,101,128,161,203,256,322,406,512};
__device__ const int dRes[NL] = {16,20,25,32,40,50,64,80,101,128,161,203,256,322,406,512};

// ---------------- pre-pass: pack emb (L,2,NE) fp32 -> (L,NE) u32 of 2x bf16 ----------------
__global__ void pack_kernel(const float* __restrict__ emb, uint32_t* __restrict__ tbl) {
    int i = blockIdx.x * blockDim.x + threadIdx.x;     // 0 .. NL*NE-1
    if (i >= NL * NE) return;
    int l = i >> 14;
    int j = i & (NE - 1);
    float e0 = emb[(size_t)l * 2 * NE + j];
    float e1 = emb[(size_t)l * 2 * NE + NE + j];
    uint32_t u0 = __float_as_uint(e0); u0 = (u0 + 0x7fffu + ((u0 >> 16) & 1u)) >> 16;  // RTNE bf16
    uint32_t u1 = __float_as_uint(e1); u1 = (u1 + 0x7fffu + ((u1 >> 16) & 1u)) >> 16;
    tbl[i] = u0 | (u1 << 16);
}

// ---------------- pass 1: LEVEL-MAJOR, table staged once, barrier-free gather loop ----------------
// (unchanged from R11 -- measured ~70 us; held fixed while pass 2 is rebuilt)
__global__ __launch_bounds__(BLK1, 4)   // 64-VGPR budget
void level_kernel(const float* __restrict__ x, const uint32_t* __restrict__ tbl,
                  uint32_t* __restrict__ mid) {
    __shared__ __align__(16) uint32_t lds[NE];         // 64 KB: this level's full table

    const int tid   = threadIdx.x;
    const int level = blockIdx.x & (NL - 1);
    const int chunk = blockIdx.x >> 4;

    {
        const uint4* g = (const uint4*)(tbl + ((size_t)level << 14));
        uint4* dst = (uint4*)lds;
        #pragma unroll
        for (int p = 0; p < 8; ++p) dst[p * BLK1 + tid] = g[p * BLK1 + tid];
    }
    __syncthreads();                                   // only barrier in the kernel

    const int   res  = dRes[level];
    const float hres = 0.5f * (float)res;              // unnorm: ix = p*hres + (hres-0.5)
    const float cadd = hres - 0.5f;
    const bool hashed = (res * res * res > NE);

    uint32_t* dst = mid + ((size_t)level << 21);
    const float3* xs = (const float3*)x;
    const size_t pbase = (size_t)chunk * PPB + tid;

    if (hashed) {
        float3 nxt = xs[pbase];
        for (int i = 0; i < ITER; ++i) {
            const float3 cur = nxt;
            if (i + 1 < ITER) nxt = xs[pbase + (size_t)(i + 1) * BLK1];  // preload
            const float pc[3] = {cur.x, cur.y, cur.z};

            float    w[3][2];
            uint32_t a[3][2];
            #pragma unroll
            for (int d = 0; d < 3; ++d) {
                constexpr uint32_t P[3] = {1u, 2654435761u, 805459861u};
                float ix = fmaf(pc[d], hres, cadd);
                float fl = floorf(ix);
                const float fr = ix - fl;
                const int lo = (int)fl;                 // in [-1, res-1], NO clamp
                w[d][0] = (lo >= 0)       ? (1.0f - fr) : 0.0f;   // zero-padding
                w[d][1] = (lo + 1 <= res - 1) ? fr      : 0.0f;
                a[d][0] = (uint32_t)lo * P[d];
                a[d][1] = a[d][0] + P[d];
            }

            float    wxy[4];
            uint32_t axy[4];
            #pragma unroll
            for (int c = 0; c < 4; ++c) {
                wxy[c] = w[0][c & 1] * w[1][(c >> 1) & 1];
                axy[c] = a[0][c & 1] ^ a[1][(c >> 1) & 1];
            }

            float f0 = 0.0f, f1 = 0.0f;
            #pragma unroll
            for (int c = 0; c < 8; ++c) {
                const int cxy = c & 3, bz = (c >> 2) & 1;
                const uint32_t idx = (axy[cxy] ^ a[2][bz]) & (uint32_t)(NE - 1);
                const float wt = wxy[cxy] * w[2][bz];
                const uint32_t v = lds[idx];
                f0 = fmaf(wt, __uint_as_float(v << 16),          f0);
                f1 = fmaf(wt, __uint_as_float(v & 0xffff0000u),  f1);
            }

            const uint32_t u0 = (__float_as_uint(f0) + 0x8000u) >> 16;
            const uint32_t u1 = (__float_as_uint(f1) + 0x8000u) & 0xffff0000u;
            dst[pbase + (size_t)i * BLK1] = u0 | u1;
        }
    } else {                                            // direct levels (0..2): clamps needed
        const uint32_t sy = (uint32_t)res, sz = (uint32_t)(res * res);
        float3 nxt = xs[pbase];
        for (int i = 0; i < ITER; ++i) {
            const float3 cur = nxt;
            if (i + 1 < ITER) nxt = xs[pbase + (size_t)(i + 1) * BLK1];
            const float pc[3] = {cur.x, cur.y, cur.z};

            float    w[3][2];
            uint32_t a[3][2];
            #pragma unroll
            for (int d = 0; d < 3; ++d) {
                const uint32_t stride = (d == 0) ? 1u : ((d == 1) ? sy : sz);
                float ix = fmaf(pc[d], hres, cadd);
                float fl = floorf(ix);
                const float fr = ix - fl;
                const int lo = (int)fl, hi = lo + 1;
                w[d][0] = (lo >= 0)       ? (1.0f - fr) : 0.0f;
                w[d][1] = (hi <= res - 1) ? fr          : 0.0f;
                const int loc = lo < 0 ? 0 : lo;
                const int hic = hi > res - 1 ? res - 1 : hi;
                a[d][0] = (uint32_t)loc * stride;
                a[d][1] = (uint32_t)hic * stride;
            }

            float    wxy[4];
            uint32_t axy[4];
            #pragma unroll
            for (int c = 0; c < 4; ++c) {
                wxy[c] = w[0][c & 1] * w[1][(c >> 1) & 1];
                axy[c] = a[0][c & 1] + a[1][(c >> 1) & 1];
            }

            float f0 = 0.0f, f1 = 0.0f;
            #pragma unroll
            for (int c = 0; c < 8; ++c) {
                const int cxy = c & 3, bz = (c >> 2) & 1;
                const uint32_t idx = axy[cxy] + a[2][bz];
                const float wt = wxy[cxy] * w[2][bz];
                const uint32_t v = lds[idx];
                f0 = fmaf(wt, __uint_as_float(v << 16),          f0);
                f1 = fmaf(wt, __uint_as_float(v & 0xffff0000u),  f1);
            }

            const uint32_t u0 = (__float_as_uint(f0) + 0x8000u) >> 16;
            const uint32_t u1 = (__float_as_uint(f1) + 0x8000u) & 0xffff0000u;
            dst[pbase + (size_t)i * BLK1] = u0 | u1;
        }
    }
}

// ------------- pass 2: LDS-tiled transpose (L,B) u32 -> (B,L,2) fp32 -------------
// Read: per level, two fully-coalesced 1-KB u32 stream reads (thread t -> points t, t+256).
// Write: 16 iters of lane-contiguous float4 stores -- each wave instruction covers 4 KB of
// CONSECUTIVE output (full 128-B lines only; kills the R11 write-amplification RMW).
// LDS tile [TP][17]: pad 17 makes deposit banks 17*t mod 32 (2-way, free) and fetch <=4-way.
__global__ __launch_bounds__(BLK2, 4)
void transpose_kernel(const uint32_t* __restrict__ mid, float* __restrict__ out) {
    __shared__ uint32_t t[TP * 17];

    const int tid = threadIdx.x;
    const size_t base_p = (size_t)blockIdx.x * TP;

    #pragma unroll
    for (int l = 0; l < NL; ++l) {
        const uint32_t* s = mid + ((size_t)l << 21) + base_p;
        t[tid * 17 + l]         = s[tid];              // coalesced 1 KB
        t[(tid + 256) * 17 + l] = s[tid + 256];        // coalesced 1 KB
    }
    __syncthreads();

    float4* o = (float4*)(out + base_p * 32);          // float4 index: p*8 + q
    #pragma unroll
    for (int it = 0; it < 16; ++it) {
        const int f = it * BLK2 + tid;                 // 0..4095
        const int p = f >> 3, q = f & 7;
        const uint32_t v0 = t[p * 17 + 2 * q];
        const uint32_t v1 = t[p * 17 + 2 * q + 1];
        o[f] = make_float4(__uint_as_float(v0 << 16), __uint_as_float(v0 & 0xffff0000u),
                           __uint_as_float(v1 << 16), __uint_as_float(v1 & 0xffff0000u));
    }
}

// ---------------- fallback: R6 point-major kernel (proven ~230-260 us) if ws too small ----------------
__global__ __launch_bounds__(BLKF, 4)
void hashenc_kernel(const float* __restrict__ x, const uint32_t* __restrict__ tbl,
                    float* __restrict__ out) {
    __shared__ __align__(16) uint32_t lds[NE];

    const int tid  = threadIdx.x;
    const size_t b = (size_t)blockIdx.x * BLKF + tid;

    const float3 p3 = ((const float3*)x)[b];
    const float pc[3] = {p3.x, p3.y, p3.z};

    {
        const uint4* g = (const uint4*)tbl;
        uint4 r0 = g[0 * BLKF + tid], r1 = g[1 * BLKF + tid];
        uint4 r2 = g[2 * BLKF + tid], r3 = g[3 * BLKF + tid];
        uint4* dst = (uint4*)lds;
        dst[0 * BLKF + tid] = r0; dst[1 * BLKF + tid] = r1;
        dst[2 * BLKF + tid] = r2; dst[3 * BLKF + tid] = r3;
    }

    float acc[16];
    #pragma unroll
    for (int i = 0; i < 16; ++i) acc[i] = 0.0f;

    #pragma unroll
    for (int l = 0; l < NL; ++l) {
        __syncthreads();

        uint4 r0, r1, r2, r3;
        if (l + 1 < NL) {
            const uint4* g = (const uint4*)(tbl + ((size_t)(l + 1) << 14));
            r0 = g[0 * BLKF + tid]; r1 = g[1 * BLKF + tid];
            r2 = g[2 * BLKF + tid]; r3 = g[3 * BLKF + tid];
        }

        const int   res  = kRes[l];
        const float hres = 0.5f * (float)res;
        const float cadd = hres - 0.5f;
        const bool hashed = (res * res * res > NE);

        float fr[3]; int c0[3];
        #pragma unroll
        for (int d = 0; d < 3; ++d) {
            float ix = fmaf(pc[d], hres, cadd);
            float fl = floorf(ix);
            fr[d] = ix - fl;
            c0[d] = (int)fl;
        }

        float    w[3][2];
        uint32_t a[3][2];
        #pragma unroll
        for (int d = 0; d < 3; ++d) {
            const int lo = c0[d], hi = c0[d] + 1;
            w[d][0] = (lo >= 0)     ? (1.0f - fr[d]) : 0.0f;
            w[d][1] = (hi <= res-1) ? fr[d]          : 0.0f;
            const int loc = lo < 0 ? 0 : lo;
            const int hic = hi > res - 1 ? res - 1 : hi;
            if (hashed) {
                constexpr uint32_t P[3] = {1u, 2654435761u, 805459861u};
                a[d][0] = (uint32_t)loc * P[d];
                a[d][1] = (uint32_t)hic * P[d];
            } else {
                const uint32_t stride = (d == 0) ? 1u : ((d == 1) ? (uint32_t)res
                                                                  : (uint32_t)(res * res));
                a[d][0] = (uint32_t)loc * stride;
                a[d][1] = (uint32_t)hic * stride;
            }
        }

        float    wxy[4];
        uint32_t axy[4];
        #pragma unroll
        for (int c = 0; c < 4; ++c) {
            const int bx = c & 1, by = (c >> 1) & 1;
            wxy[c] = w[0][bx] * w[1][by];
            axy[c] = hashed ? (a[0][bx] ^ a[1][by]) : (a[0][bx] + a[1][by]);
        }

        float f0 = 0.0f, f1 = 0.0f;
        #pragma unroll
        for (int c = 0; c < 8; ++c) {
            const int cxy = c & 3, bz = (c >> 2) & 1;
            const uint32_t idx = hashed
                ? ((axy[cxy] ^ a[2][bz]) & (uint32_t)(NE - 1))
                : (axy[cxy] + a[2][bz]);
            const float wt = wxy[cxy] * w[2][bz];
            const uint32_t v = lds[idx];
            f0 = fmaf(wt, __uint_as_float(v << 16),          f0);
            f1 = fmaf(wt, __uint_as_float(v & 0xffff0000u),  f1);
        }
        acc[2 * (l & 7) + 0] = f0;
        acc[2 * (l & 7) + 1] = f1;

        if (l + 1 < NL) {
            __syncthreads();
            uint4* dst = (uint4*)lds;
            dst[0 * BLKF + tid] = r0; dst[1 * BLKF + tid] = r1;
            dst[2 * BLKF + tid] = r2; dst[3 * BLKF + tid] = r3;
        }

        if ((l & 7) == 7) {
            float4* o = (float4*)(out + b * 32 + (size_t)(l >> 3) * 16);
            o[0] = make_float4(acc[0],  acc[1],  acc[2],  acc[3]);
            o[1] = make_float4(acc[4],  acc[5],  acc[6],  acc[7]);
            o[2] = make_float4(acc[8],  acc[9],  acc[10], acc[11]);
            o[3] = make_float4(acc[12], acc[13], acc[14], acc[15]);
        }
    }
}

extern "C" void kernel_launch(void* const* d_in, const int* in_sizes, int n_in,
                              void* d_out, int out_size, void* d_ws, size_t ws_size,
                              hipStream_t stream) {
    const float* x   = (const float*)d_in[0];   // (B,3) fp32
    const float* emb = (const float*)d_in[1];   // (16,2,16384) fp32
    float* out = (float*)d_out;                 // (B,16,2) fp32

    uint32_t* tbl = (uint32_t*)d_ws;            // (16,16384) packed bf16x2 = 1 MB
    const size_t tbl_bytes = (size_t)NL * NE * 4;
    const size_t mid_bytes = (size_t)NL * (1 << 21) * 4;   // 128 MB intermediate

    const int npack = NL * NE;
    pack_kernel<<<dim3((npack + 255) / 256), dim3(256), 0, stream>>>(emb, tbl);

    if (ws_size >= tbl_bytes + mid_bytes) {
        uint32_t* mid = tbl + (size_t)NL * NE;
        level_kernel<<<dim3(NL * NB), dim3(BLK1), 0, stream>>>(x, tbl, mid);
        transpose_kernel<<<dim3((1 << 21) / TP), dim3(BLK2), 0, stream>>>(mid, out);
    } else {
        hashenc_kernel<<<dim3((1 << 21) / BLKF), dim3(BLKF), 0, stream>>>(x, tbl, out);
    }
}

// Round 14
// 172.899 us; speedup vs baseline: 1.8608x; 1.0621x over previous
//
#include <hip/hip_runtime.h>
#include <stdint.h>

#define NL  16
#define NE  16384               // entries per level (power of two)
#define NB  64                  // chunks per level in pass 1
#define BLK1 512                // pass-1 threads per block
#define PPB  ((1 << 21) / NB)   // 32768 points per pass-1 block
#define ITER (PPB / BLK1)       // 64 points per thread
#define BLK2 256                // pass-2 threads per block
#define TP   512                // pass-2 points per block (LDS tile)
#define BLKF 1024               // fallback threads per block

typedef unsigned int uint2_v  __attribute__((ext_vector_type(2)));   // native clang vectors:
typedef float        float4_v __attribute__((ext_vector_type(4)));   // nontemporal builtins
                                                                     // reject HIP_vector_type
constexpr int kRes[NL] = {16,20,25,32,40,50,64,80,101,128,161,203,256,322,406,512};
__device__ const int dRes[NL] = {16,20,25,32,40,50,64,80,101,128,161,203,256,322,406,512};

__device__ __forceinline__ uint32_t bf16_rtne(float f) {
    uint32_t u = __float_as_uint(f);
    return (u + 0x7fffu + ((u >> 16) & 1u)) >> 16;     // round-to-nearest-even
}

// ---------------- pre-pass (FALLBACK PATH ONLY): pack emb fp32 -> packed bf16x2 ----------------
__global__ void pack_kernel(const float* __restrict__ emb, uint32_t* __restrict__ tbl) {
    int i = blockIdx.x * blockDim.x + threadIdx.x;     // 0 .. NL*NE-1
    if (i >= NL * NE) return;
    int l = i >> 14;
    int j = i & (NE - 1);
    float e0 = emb[(size_t)l * 2 * NE + j];
    float e1 = emb[(size_t)l * 2 * NE + NE + j];
    tbl[i] = bf16_rtne(e0) | (bf16_rtne(e1) << 16);
}

// ---------------- pass 1: LEVEL-MAJOR, fused pack+stage, barrier-free gather loop ----------------
// Each block reads its level's fp32 table straight from emb (L3-resident), converts to packed
// bf16x2 with the same RTNE rounding, stages to LDS once, then free-runs the gather loop.
// mid stores are non-temporal: written once, read once by pass 2, far larger than L2.
__global__ __launch_bounds__(BLK1, 4)   // 64-VGPR budget
void level_kernel(const float* __restrict__ x, const float* __restrict__ emb,
                  uint32_t* __restrict__ mid) {
    __shared__ __align__(16) uint32_t lds[NE];         // 64 KB: this level's full table

    const int tid   = threadIdx.x;
    const int level = blockIdx.x & (NL - 1);
    const int chunk = blockIdx.x >> 4;

    // fused pack + stage: 8 iters x (2 float4 loads -> 1 uint4 ds_write), fully coalesced
    {
        const float4* e0s = (const float4*)(emb + (size_t)level * 2 * NE);
        const float4* e1s = (const float4*)(emb + (size_t)level * 2 * NE + NE);
        uint4* dst = (uint4*)lds;
        #pragma unroll
        for (int p = 0; p < 8; ++p) {
            const float4 a = e0s[p * BLK1 + tid];
            const float4 b = e1s[p * BLK1 + tid];
            uint4 v;
            v.x = bf16_rtne(a.x) | (bf16_rtne(b.x) << 16);
            v.y = bf16_rtne(a.y) | (bf16_rtne(b.y) << 16);
            v.z = bf16_rtne(a.z) | (bf16_rtne(b.z) << 16);
            v.w = bf16_rtne(a.w) | (bf16_rtne(b.w) << 16);
            dst[p * BLK1 + tid] = v;
        }
    }
    __syncthreads();                                   // only barrier in the kernel

    const int   res  = dRes[level];
    const float hres = 0.5f * (float)res;              // unnorm: ix = p*hres + (hres-0.5)
    const float cadd = hres - 0.5f;
    const bool hashed = (res * res * res > NE);

    uint32_t* dst = mid + ((size_t)level << 21);
    const float3* xs = (const float3*)x;
    const size_t pbase = (size_t)chunk * PPB + tid;

    if (hashed) {
        float3 nxt = xs[pbase];
        for (int i = 0; i < ITER; ++i) {
            const float3 cur = nxt;
            if (i + 1 < ITER) nxt = xs[pbase + (size_t)(i + 1) * BLK1];  // preload
            const float pc[3] = {cur.x, cur.y, cur.z};

            float    w[3][2];
            uint32_t a[3][2];
            #pragma unroll
            for (int d = 0; d < 3; ++d) {
                constexpr uint32_t P[3] = {1u, 2654435761u, 805459861u};
                float ix = fmaf(pc[d], hres, cadd);
                float fl = floorf(ix);
                const float fr = ix - fl;
                const int lo = (int)fl;                 // in [-1, res-1], NO clamp
                w[d][0] = (lo >= 0)       ? (1.0f - fr) : 0.0f;   // zero-padding
                w[d][1] = (lo + 1 <= res - 1) ? fr      : 0.0f;
                a[d][0] = (uint32_t)lo * P[d];
                a[d][1] = a[d][0] + P[d];
            }

            float    wxy[4];
            uint32_t axy[4];
            #pragma unroll
            for (int c = 0; c < 4; ++c) {
                wxy[c] = w[0][c & 1] * w[1][(c >> 1) & 1];
                axy[c] = a[0][c & 1] ^ a[1][(c >> 1) & 1];
            }

            float f0 = 0.0f, f1 = 0.0f;
            #pragma unroll
            for (int c = 0; c < 8; ++c) {
                const int cxy = c & 3, bz = (c >> 2) & 1;
                const uint32_t idx = (axy[cxy] ^ a[2][bz]) & (uint32_t)(NE - 1);
                const float wt = wxy[cxy] * w[2][bz];
                const uint32_t v = lds[idx];
                f0 = fmaf(wt, __uint_as_float(v << 16),          f0);
                f1 = fmaf(wt, __uint_as_float(v & 0xffff0000u),  f1);
            }

            const uint32_t u0 = (__float_as_uint(f0) + 0x8000u) >> 16;
            const uint32_t u1 = (__float_as_uint(f1) + 0x8000u) & 0xffff0000u;
            __builtin_nontemporal_store(u0 | u1, &dst[pbase + (size_t)i * BLK1]);
        }
    } else {                                            // direct levels (0..2): clamps needed
        const uint32_t sy = (uint32_t)res, sz = (uint32_t)(res * res);
        float3 nxt = xs[pbase];
        for (int i = 0; i < ITER; ++i) {
            const float3 cur = nxt;
            if (i + 1 < ITER) nxt = xs[pbase + (size_t)(i + 1) * BLK1];
            const float pc[3] = {cur.x, cur.y, cur.z};

            float    w[3][2];
            uint32_t a[3][2];
            #pragma unroll
            for (int d = 0; d < 3; ++d) {
                const uint32_t stride = (d == 0) ? 1u : ((d == 1) ? sy : sz);
                float ix = fmaf(pc[d], hres, cadd);
                float fl = floorf(ix);
                const float fr = ix - fl;
                const int lo = (int)fl, hi = lo + 1;
                w[d][0] = (lo >= 0)       ? (1.0f - fr) : 0.0f;
                w[d][1] = (hi <= res - 1) ? fr          : 0.0f;
                const int loc = lo < 0 ? 0 : lo;
                const int hic = hi > res - 1 ? res - 1 : hi;
                a[d][0] = (uint32_t)loc * stride;
                a[d][1] = (uint32_t)hic * stride;
            }

            float    wxy[4];
            uint32_t axy[4];
            #pragma unroll
            for (int c = 0; c < 4; ++c) {
                wxy[c] = w[0][c & 1] * w[1][(c >> 1) & 1];
                axy[c] = a[0][c & 1] + a[1][(c >> 1) & 1];
            }

            float f0 = 0.0f, f1 = 0.0f;
            #pragma unroll
            for (int c = 0; c < 8; ++c) {
                const int cxy = c & 3, bz = (c >> 2) & 1;
                const uint32_t idx = axy[cxy] + a[2][bz];
                const float wt = wxy[cxy] * w[2][bz];
                const uint32_t v = lds[idx];
                f0 = fmaf(wt, __uint_as_float(v << 16),          f0);
                f1 = fmaf(wt, __uint_as_float(v & 0xffff0000u),  f1);
            }

            const uint32_t u0 = (__float_as_uint(f0) + 0x8000u) >> 16;
            const uint32_t u1 = (__float_as_uint(f1) + 0x8000u) & 0xffff0000u;
            __builtin_nontemporal_store(u0 | u1, &dst[pbase + (size_t)i * BLK1]);
        }
    }
}

// ------------- pass 2: LDS-tiled transpose (L,B) u32 -> (B,L,2) fp32 -------------
// Reads: uint2 per thread per level (8 B/lane, 2 KB/wave-instr), non-temporal.
// Deposit rows 2t,2t+1 with pad 17: bank (2t+17k+l)%32 -> 2-way aliasing (free, m136).
// Writes: lane-contiguous float4, full 128-B lines only, non-temporal.
__global__ __launch_bounds__(BLK2, 4)
void transpose_kernel(const uint32_t* __restrict__ mid, float* __restrict__ out) {
    __shared__ uint32_t t[TP * 17];

    const int tid = threadIdx.x;
    const size_t base_p = (size_t)blockIdx.x * TP;

    #pragma unroll
    for (int l = 0; l < NL; ++l) {
        const uint2_v* s = (const uint2_v*)(mid + ((size_t)l << 21) + base_p);
        const uint2_v v = __builtin_nontemporal_load(&s[tid]);
        t[(2 * tid) * 17 + l]     = v.x;
        t[(2 * tid + 1) * 17 + l] = v.y;
    }
    __syncthreads();

    float4_v* o = (float4_v*)(out + base_p * 32);      // float4 index: p*8 + q
    #pragma unroll
    for (int it = 0; it < 16; ++it) {
        const int f = it * BLK2 + tid;                 // 0..4095
        const int p = f >> 3, q = f & 7;
        const uint32_t v0 = t[p * 17 + 2 * q];
        const uint32_t v1 = t[p * 17 + 2 * q + 1];
        float4_v val;
        val.x = __uint_as_float(v0 << 16);
        val.y = __uint_as_float(v0 & 0xffff0000u);
        val.z = __uint_as_float(v1 << 16);
        val.w = __uint_as_float(v1 & 0xffff0000u);
        __builtin_nontemporal_store(val, &o[f]);
    }
}

// ---------------- fallback: R6 point-major kernel (proven ~230-260 us) if ws too small ----------------
__global__ __launch_bounds__(BLKF, 4)
void hashenc_kernel(const float* __restrict__ x, const uint32_t* __restrict__ tbl,
                    float* __restrict__ out) {
    __shared__ __align__(16) uint32_t lds[NE];

    const int tid  = threadIdx.x;
    const size_t b = (size_t)blockIdx.x * BLKF + tid;

    const float3 p3 = ((const float3*)x)[b];
    const float pc[3] = {p3.x, p3.y, p3.z};

    {
        const uint4* g = (const uint4*)tbl;
        uint4 r0 = g[0 * BLKF + tid], r1 = g[1 * BLKF + tid];
        uint4 r2 = g[2 * BLKF + tid], r3 = g[3 * BLKF + tid];
        uint4* dst = (uint4*)lds;
        dst[0 * BLKF + tid] = r0; dst[1 * BLKF + tid] = r1;
        dst[2 * BLKF + tid] = r2; dst[3 * BLKF + tid] = r3;
    }

    float acc[16];
    #pragma unroll
    for (int i = 0; i < 16; ++i) acc[i] = 0.0f;

    #pragma unroll
    for (int l = 0; l < NL; ++l) {
        __syncthreads();

        uint4 r0, r1, r2, r3;
        if (l + 1 < NL) {
            const uint4* g = (const uint4*)(tbl + ((size_t)(l + 1) << 14));
            r0 = g[0 * BLKF + tid]; r1 = g[1 * BLKF + tid];
            r2 = g[2 * BLKF + tid]; r3 = g[3 * BLKF + tid];
        }

        const int   res  = kRes[l];
        const float hres = 0.5f * (float)res;
        const float cadd = hres - 0.5f;
        const bool hashed = (res * res * res > NE);

        float fr[3]; int c0[3];
        #pragma unroll
        for (int d = 0; d < 3; ++d) {
            float ix = fmaf(pc[d], hres, cadd);
            float fl = floorf(ix);
            fr[d] = ix - fl;
            c0[d] = (int)fl;
        }

        float    w[3][2];
        uint32_t a[3][2];
        #pragma unroll
        for (int d = 0; d < 3; ++d) {
            const int lo = c0[d], hi = c0[d] + 1;
            w[d][0] = (lo >= 0)     ? (1.0f - fr[d]) : 0.0f;
            w[d][1] = (hi <= res-1) ? fr[d]          : 0.0f;
            const int loc = lo < 0 ? 0 : lo;
            const int hic = hi > res - 1 ? res - 1 : hi;
            if (hashed) {
                constexpr uint32_t P[3] = {1u, 2654435761u, 805459861u};
                a[d][0] = (uint32_t)loc * P[d];
                a[d][1] = (uint32_t)hic * P[d];
            } else {
                const uint32_t stride = (d == 0) ? 1u : ((d == 1) ? (uint32_t)res
                                                                  : (uint32_t)(res * res));
                a[d][0] = (uint32_t)loc * stride;
                a[d][1] = (uint32_t)hic * stride;
            }
        }

        float    wxy[4];
        uint32_t axy[4];
        #pragma unroll
        for (int c = 0; c < 4; ++c) {
            const int bx = c & 1, by = (c >> 1) & 1;
            wxy[c] = w[0][bx] * w[1][by];
            axy[c] = hashed ? (a[0][bx] ^ a[1][by]) : (a[0][bx] + a[1][by]);
        }

        float f0 = 0.0f, f1 = 0.0f;
        #pragma unroll
        for (int c = 0; c < 8; ++c) {
            const int cxy = c & 3, bz = (c >> 2) & 1;
            const uint32_t idx = hashed
                ? ((axy[cxy] ^ a[2][bz]) & (uint32_t)(NE - 1))
                : (axy[cxy] + a[2][bz]);
            const float wt = wxy[cxy] * w[2][bz];
            const uint32_t v = lds[idx];
            f0 = fmaf(wt, __uint_as_float(v << 16),          f0);
            f1 = fmaf(wt, __uint_as_float(v & 0xffff0000u),  f1);
        }
        acc[2 * (l & 7) + 0] = f0;
        acc[2 * (l & 7) + 1] = f1;

        if (l + 1 < NL) {
            __syncthreads();
            uint4* dst = (uint4*)lds;
            dst[0 * BLKF + tid] = r0; dst[1 * BLKF + tid] = r1;
            dst[2 * BLKF + tid] = r2; dst[3 * BLKF + tid] = r3;
        }

        if ((l & 7) == 7) {
            float4* o = (float4*)(out + b * 32 + (size_t)(l >> 3) * 16);
            o[0] = make_float4(acc[0],  acc[1],  acc[2],  acc[3]);
            o[1] = make_float4(acc[4],  acc[5],  acc[6],  acc[7]);
            o[2] = make_float4(acc[8],  acc[9],  acc[10], acc[11]);
            o[3] = make_float4(acc[12], acc[13], acc[14], acc[15]);
        }
    }
}

extern "C" void kernel_launch(void* const* d_in, const int* in_sizes, int n_in,
                              void* d_out, int out_size, void* d_ws, size_t ws_size,
                              hipStream_t stream) {
    const float* x   = (const float*)d_in[0];   // (B,3) fp32
    const float* emb = (const float*)d_in[1];   // (16,2,16384) fp32
    float* out = (float*)d_out;                 // (B,16,2) fp32

    const size_t mid_bytes = (size_t)NL * (1 << 21) * 4;   // 128 MB intermediate
    const size_t tbl_bytes = (size_t)NL * NE * 4;

    if (ws_size >= mid_bytes) {
        uint32_t* mid = (uint32_t*)d_ws;
        level_kernel<<<dim3(NL * NB), dim3(BLK1), 0, stream>>>(x, emb, mid);
        transpose_kernel<<<dim3((1 << 21) / TP), dim3(BLK2), 0, stream>>>(mid, out);
    } else if (ws_size >= tbl_bytes) {
        uint32_t* tbl = (uint32_t*)d_ws;
        const int npack = NL * NE;
        pack_kernel<<<dim3((npack + 255) / 256), dim3(256), 0, stream>>>(emb, tbl);
        hashenc_kernel<<<dim3((1 << 21) / BLKF), dim3(BLKF), 0, stream>>>(x, tbl, out);
    }
}

// Round 15
// 161.621 us; speedup vs baseline: 1.9907x; 1.0698x over previous
//
#include <hip/hip_runtime.h>
#include <stdint.h>

#define NL  16
#define NE  16384               // entries per level (power of two)
#define NB  64                  // chunks per level in pass 1
#define BLK1 512                // pass-1 threads per block
#define PPB  ((1 << 21) / NB)   // 32768 points per pass-1 block
#define ITER (PPB / BLK1)       // 64 points per thread
#define BLK2 256                // pass-2 threads per block
#define TP   512                // pass-2 points per block (LDS tile)
#define BLKF 1024               // fallback threads per block

typedef float float4_v __attribute__((ext_vector_type(4)));   // native vec for nt builtin

constexpr int kRes[NL] = {16,20,25,32,40,50,64,80,101,128,161,203,256,322,406,512};
__device__ const int dRes[NL] = {16,20,25,32,40,50,64,80,101,128,161,203,256,322,406,512};

__device__ __forceinline__ uint32_t bf16_rtne(float f) {
    uint32_t u = __float_as_uint(f);
    return (u + 0x7fffu + ((u >> 16) & 1u)) >> 16;     // round-to-nearest-even
}

// ---------------- pre-pass (FALLBACK PATH ONLY): pack emb fp32 -> packed bf16x2 ----------------
__global__ void pack_kernel(const float* __restrict__ emb, uint32_t* __restrict__ tbl) {
    int i = blockIdx.x * blockDim.x + threadIdx.x;     // 0 .. NL*NE-1
    if (i >= NL * NE) return;
    int l = i >> 14;
    int j = i & (NE - 1);
    float e0 = emb[(size_t)l * 2 * NE + j];
    float e1 = emb[(size_t)l * 2 * NE + NE + j];
    tbl[i] = bf16_rtne(e0) | (bf16_rtne(e1) << 16);
}

// ---------------- pass 1: LEVEL-MAJOR, fused pack+stage, barrier-free gather loop ----------------
// mid stores are PLAIN (not nt): mid is 128 MB and fits the 256-MB L3, so pass 2's read side
// can be served from L3 dirty lines instead of HBM. nt belongs only on `out` (never re-read).
__global__ __launch_bounds__(BLK1, 4)   // 64-VGPR budget
void level_kernel(const float* __restrict__ x, const float* __restrict__ emb,
                  uint32_t* __restrict__ mid) {
    __shared__ __align__(16) uint32_t lds[NE];         // 64 KB: this level's full table

    const int tid   = threadIdx.x;
    const int level = blockIdx.x & (NL - 1);
    const int chunk = blockIdx.x >> 4;

    // fused pack + stage: 8 iters x (2 float4 loads -> 1 uint4 ds_write), fully coalesced
    {
        const float4* e0s = (const float4*)(emb + (size_t)level * 2 * NE);
        const float4* e1s = (const float4*)(emb + (size_t)level * 2 * NE + NE);
        uint4* dst = (uint4*)lds;
        #pragma unroll
        for (int p = 0; p < 8; ++p) {
            const float4 a = e0s[p * BLK1 + tid];
            const float4 b = e1s[p * BLK1 + tid];
            uint4 v;
            v.x = bf16_rtne(a.x) | (bf16_rtne(b.x) << 16);
            v.y = bf16_rtne(a.y) | (bf16_rtne(b.y) << 16);
            v.z = bf16_rtne(a.z) | (bf16_rtne(b.z) << 16);
            v.w = bf16_rtne(a.w) | (bf16_rtne(b.w) << 16);
            dst[p * BLK1 + tid] = v;
        }
    }
    __syncthreads();                                   // only barrier in the kernel

    const int   res  = dRes[level];
    const float hres = 0.5f * (float)res;              // unnorm: ix = p*hres + (hres-0.5)
    const float cadd = hres - 0.5f;
    const bool hashed = (res * res * res > NE);

    uint32_t* dst = mid + ((size_t)level << 21);
    const float3* xs = (const float3*)x;
    const size_t pbase = (size_t)chunk * PPB + tid;

    if (hashed) {
        float3 nxt = xs[pbase];
        for (int i = 0; i < ITER; ++i) {
            const float3 cur = nxt;
            if (i + 1 < ITER) nxt = xs[pbase + (size_t)(i + 1) * BLK1];  // preload
            const float pc[3] = {cur.x, cur.y, cur.z};

            float    w[3][2];
            uint32_t a[3][2];
            #pragma unroll
            for (int d = 0; d < 3; ++d) {
                constexpr uint32_t P[3] = {1u, 2654435761u, 805459861u};
                float ix = fmaf(pc[d], hres, cadd);
                float fl = floorf(ix);
                const float fr = ix - fl;
                const int lo = (int)fl;                 // in [-1, res-1], NO clamp
                w[d][0] = (lo >= 0)       ? (1.0f - fr) : 0.0f;   // zero-padding
                w[d][1] = (lo + 1 <= res - 1) ? fr      : 0.0f;
                a[d][0] = (uint32_t)lo * P[d];
                a[d][1] = a[d][0] + P[d];
            }

            float    wxy[4];
            uint32_t axy[4];
            #pragma unroll
            for (int c = 0; c < 4; ++c) {
                wxy[c] = w[0][c & 1] * w[1][(c >> 1) & 1];
                axy[c] = a[0][c & 1] ^ a[1][(c >> 1) & 1];
            }

            float f0 = 0.0f, f1 = 0.0f;
            #pragma unroll
            for (int c = 0; c < 8; ++c) {
                const int cxy = c & 3, bz = (c >> 2) & 1;
                const uint32_t idx = (axy[cxy] ^ a[2][bz]) & (uint32_t)(NE - 1);
                const float wt = wxy[cxy] * w[2][bz];
                const uint32_t v = lds[idx];
                f0 = fmaf(wt, __uint_as_float(v << 16),          f0);
                f1 = fmaf(wt, __uint_as_float(v & 0xffff0000u),  f1);
            }

            const uint32_t u0 = (__float_as_uint(f0) + 0x8000u) >> 16;
            const uint32_t u1 = (__float_as_uint(f1) + 0x8000u) & 0xffff0000u;
            dst[pbase + (size_t)i * BLK1] = u0 | u1;    // plain store: keep in L3 for pass 2
        }
    } else {                                            // direct levels (0..2): clamps needed
        const uint32_t sy = (uint32_t)res, sz = (uint32_t)(res * res);
        float3 nxt = xs[pbase];
        for (int i = 0; i < ITER; ++i) {
            const float3 cur = nxt;
            if (i + 1 < ITER) nxt = xs[pbase + (size_t)(i + 1) * BLK1];
            const float pc[3] = {cur.x, cur.y, cur.z};

            float    w[3][2];
            uint32_t a[3][2];
            #pragma unroll
            for (int d = 0; d < 3; ++d) {
                const uint32_t stride = (d == 0) ? 1u : ((d == 1) ? sy : sz);
                float ix = fmaf(pc[d], hres, cadd);
                float fl = floorf(ix);
                const float fr = ix - fl;
                const int lo = (int)fl, hi = lo + 1;
                w[d][0] = (lo >= 0)       ? (1.0f - fr) : 0.0f;
                w[d][1] = (hi <= res - 1) ? fr          : 0.0f;
                const int loc = lo < 0 ? 0 : lo;
                const int hic = hi > res - 1 ? res - 1 : hi;
                a[d][0] = (uint32_t)loc * stride;
                a[d][1] = (uint32_t)hic * stride;
            }

            float    wxy[4];
            uint32_t axy[4];
            #pragma unroll
            for (int c = 0; c < 4; ++c) {
                wxy[c] = w[0][c & 1] * w[1][(c >> 1) & 1];
                axy[c] = a[0][c & 1] + a[1][(c >> 1) & 1];
            }

            float f0 = 0.0f, f1 = 0.0f;
            #pragma unroll
            for (int c = 0; c < 8; ++c) {
                const int cxy = c & 3, bz = (c >> 2) & 1;
                const uint32_t idx = axy[cxy] + a[2][bz];
                const float wt = wxy[cxy] * w[2][bz];
                const uint32_t v = lds[idx];
                f0 = fmaf(wt, __uint_as_float(v << 16),          f0);
                f1 = fmaf(wt, __uint_as_float(v & 0xffff0000u),  f1);
            }

            const uint32_t u0 = (__float_as_uint(f0) + 0x8000u) >> 16;
            const uint32_t u1 = (__float_as_uint(f1) + 0x8000u) & 0xffff0000u;
            dst[pbase + (size_t)i * BLK1] = u0 | u1;    // plain store
        }
    }
}

// ------------- pass 2: LDS-tiled transpose (L,B) u32 -> (B,L,2) fp32 -------------
// Reads: PLAIN uint2 loads (want L3 hits on the L3-resident mid).
// Writes: lane-contiguous float4 full lines, NON-TEMPORAL (out never re-read; protects
// mid's L3 residency from the 256-MB out stream).
__global__ __launch_bounds__(BLK2, 4)
void transpose_kernel(const uint32_t* __restrict__ mid, float* __restrict__ out) {
    __shared__ uint32_t t[TP * 17];

    const int tid = threadIdx.x;
    const size_t base_p = (size_t)blockIdx.x * TP;

    #pragma unroll
    for (int l = 0; l < NL; ++l) {
        const uint2* s = (const uint2*)(mid + ((size_t)l << 21) + base_p);
        const uint2 v = s[tid];                        // plain load: L3 hit expected
        t[(2 * tid) * 17 + l]     = v.x;
        t[(2 * tid + 1) * 17 + l] = v.y;
    }
    __syncthreads();

    float4_v* o = (float4_v*)(out + base_p * 32);      // float4 index: p*8 + q
    #pragma unroll
    for (int it = 0; it < 16; ++it) {
        const int f = it * BLK2 + tid;                 // 0..4095
        const int p = f >> 3, q = f & 7;
        const uint32_t v0 = t[p * 17 + 2 * q];
        const uint32_t v1 = t[p * 17 + 2 * q + 1];
        float4_v val;
        val.x = __uint_as_float(v0 << 16);
        val.y = __uint_as_float(v0 & 0xffff0000u);
        val.z = __uint_as_float(v1 << 16);
        val.w = __uint_as_float(v1 & 0xffff0000u);
        __builtin_nontemporal_store(val, &o[f]);
    }
}

// ---------------- fallback: R6 point-major kernel (proven ~230-260 us) if ws too small ----------------
__global__ __launch_bounds__(BLKF, 4)
void hashenc_kernel(const float* __restrict__ x, const uint32_t* __restrict__ tbl,
                    float* __restrict__ out) {
    __shared__ __align__(16) uint32_t lds[NE];

    const int tid  = threadIdx.x;
    const size_t b = (size_t)blockIdx.x * BLKF + tid;

    const float3 p3 = ((const float3*)x)[b];
    const float pc[3] = {p3.x, p3.y, p3.z};

    {
        const uint4* g = (const uint4*)tbl;
        uint4 r0 = g[0 * BLKF + tid], r1 = g[1 * BLKF + tid];
        uint4 r2 = g[2 * BLKF + tid], r3 = g[3 * BLKF + tid];
        uint4* dst = (uint4*)lds;
        dst[0 * BLKF + tid] = r0; dst[1 * BLKF + tid] = r1;
        dst[2 * BLKF + tid] = r2; dst[3 * BLKF + tid] = r3;
    }

    float acc[16];
    #pragma unroll
    for (int i = 0; i < 16; ++i) acc[i] = 0.0f;

    #pragma unroll
    for (int l = 0; l < NL; ++l) {
        __syncthreads();

        uint4 r0, r1, r2, r3;
        if (l + 1 < NL) {
            const uint4* g = (const uint4*)(tbl + ((size_t)(l + 1) << 14));
            r0 = g[0 * BLKF + tid]; r1 = g[1 * BLKF + tid];
            r2 = g[2 * BLKF + tid]; r3 = g[3 * BLKF + tid];
        }

        const int   res  = kRes[l];
        const float hres = 0.5f * (float)res;
        const float cadd = hres - 0.5f;
        const bool hashed = (res * res * res > NE);

        float fr[3]; int c0[3];
        #pragma unroll
        for (int d = 0; d < 3; ++d) {
            float ix = fmaf(pc[d], hres, cadd);
            float fl = floorf(ix);
            fr[d] = ix - fl;
            c0[d] = (int)fl;
        }

        float    w[3][2];
        uint32_t a[3][2];
        #pragma unroll
        for (int d = 0; d < 3; ++d) {
            const int lo = c0[d], hi = c0[d] + 1;
            w[d][0] = (lo >= 0)     ? (1.0f - fr[d]) : 0.0f;
            w[d][1] = (hi <= res-1) ? fr[d]          : 0.0f;
            const int loc = lo < 0 ? 0 : lo;
            const int hic = hi > res - 1 ? res - 1 : hi;
            if (hashed) {
                constexpr uint32_t P[3] = {1u, 2654435761u, 805459861u};
                a[d][0] = (uint32_t)loc * P[d];
                a[d][1] = (uint32_t)hic * P[d];
            } else {
                const uint32_t stride = (d == 0) ? 1u : ((d == 1) ? (uint32_t)res
                                                                  : (uint32_t)(res * res));
                a[d][0] = (uint32_t)loc * stride;
                a[d][1] = (uint32_t)hic * stride;
            }
        }

        float    wxy[4];
        uint32_t axy[4];
        #pragma unroll
        for (int c = 0; c < 4; ++c) {
            const int bx = c & 1, by = (c >> 1) & 1;
            wxy[c] = w[0][bx] * w[1][by];
            axy[c] = hashed ? (a[0][bx] ^ a[1][by]) : (a[0][bx] + a[1][by]);
        }

        float f0 = 0.0f, f1 = 0.0f;
        #pragma unroll
        for (int c = 0; c < 8; ++c) {
            const int cxy = c & 3, bz = (c >> 2) & 1;
            const uint32_t idx = hashed
                ? ((axy[cxy] ^ a[2][bz]) & (uint32_t)(NE - 1))
                : (axy[cxy] + a[2][bz]);
            const float wt = wxy[cxy] * w[2][bz];
            const uint32_t v = lds[idx];
            f0 = fmaf(wt, __uint_as_float(v << 16),          f0);
            f1 = fmaf(wt, __uint_as_float(v & 0xffff0000u),  f1);
        }
        acc[2 * (l & 7) + 0] = f0;
        acc[2 * (l & 7) + 1] = f1;

        if (l + 1 < NL) {
            __syncthreads();
            uint4* dst = (uint4*)lds;
            dst[0 * BLKF + tid] = r0; dst[1 * BLKF + tid] = r1;
            dst[2 * BLKF + tid] = r2; dst[3 * BLKF + tid] = r3;
        }

        if ((l & 7) == 7) {
            float4* o = (float4*)(out + b * 32 + (size_t)(l >> 3) * 16);
            o[0] = make_float4(acc[0],  acc[1],  acc[2],  acc[3]);
            o[1] = make_float4(acc[4],  acc[5],  acc[6],  acc[7]);
            o[2] = make_float4(acc[8],  acc[9],  acc[10], acc[11]);
            o[3] = make_float4(acc[12], acc[13], acc[14], acc[15]);
        }
    }
}

extern "C" void kernel_launch(void* const* d_in, const int* in_sizes, int n_in,
                              void* d_out, int out_size, void* d_ws, size_t ws_size,
                              hipStream_t stream) {
    const float* x   = (const float*)d_in[0];   // (B,3) fp32
    const float* emb = (const float*)d_in[1];   // (16,2,16384) fp32
    float* out = (float*)d_out;                 // (B,16,2) fp32

    const size_t mid_bytes = (size_t)NL * (1 << 21) * 4;   // 128 MB intermediate
    const size_t tbl_bytes = (size_t)NL * NE * 4;

    if (ws_size >= mid_bytes) {
        uint32_t* mid = (uint32_t*)d_ws;
        level_kernel<<<dim3(NL * NB), dim3(BLK1), 0, stream>>>(x, emb, mid);
        transpose_kernel<<<dim3((1 << 21) / TP), dim3(BLK2), 0, stream>>>(mid, out);
    } else if (ws_size >= tbl_bytes) {
        uint32_t* tbl = (uint32_t*)d_ws;
        const int npack = NL * NE;
        pack_kernel<<<dim3((npack + 255) / 256), dim3(256), 0, stream>>>(emb, tbl);
        hashenc_kernel<<<dim3((1 << 21) / BLKF), dim3(BLKF), 0, stream>>>(x, tbl, out);
    }
}